// Round 2
// baseline (135.368 us; speedup 1.0000x reference)
//
#include <hip/hip_runtime.h>

// Shapes (fixed by the reference): B=16, F=4096, M=512, D=256, VE=64, H=512, V=50, OUT=8
#define B_DIM  16
#define F_DIM  4096
#define M_DIM  512
#define D_DIM  256
#define VE_DIM 64
#define H_DIM  512
#define K_DIM  320   // D + VE
#define OUT_DIM 8

// ---------------------------------------------------------------------------
// Kernel 1 (prep):
//  blocks [0,642):   fold WcT[o][k] = sum_j W_mora[k,j] * W_post[j,o]   (wave per output)
//                    and bc[o] = sum_j b_mora[j]*W_post[j,o] + b_post[o]
//  blocks [642,898): seg[b][m] = lower_bound(mora_index[b,:], m)  via boundary detection
//                    (mora_index is sorted per batch); seg[b][M] = F
// ---------------------------------------------------------------------------
__global__ __launch_bounds__(256) void prep_kernel(
    const float* __restrict__ W_mora,            // [320,512] fp32
    const float* __restrict__ b_mora,            // [512] fp32
    const float* __restrict__ W_post,            // [512,8] fp32
    const float* __restrict__ b_post,            // [8] fp32
    const int* __restrict__ mora_index,          // [B,F] int32, sorted per batch
    float* __restrict__ WcT,                     // [8,320] fp32 out
    float* __restrict__ bc,                      // [8] fp32 out
    int* __restrict__ seg)                       // [B,513] int32 out
{
    const int blk = blockIdx.x;
    const int tid = threadIdx.x;
    if (blk < 642) {
        const int w    = blk * 4 + (tid >> 6);   // global wave id, 0..2567
        const int lane = tid & 63;
        float sum = 0.f;
        if (w < 2560) {
            const int k = w >> 3, o = w & 7;
            const float* arow = W_mora + k * H_DIM;
            #pragma unroll
            for (int it = 0; it < H_DIM / 64; ++it) {
                const int j = lane + it * 64;
                sum += arow[j] * W_post[j * OUT_DIM + o];
            }
            #pragma unroll
            for (int off = 32; off >= 1; off >>= 1) sum += __shfl_down(sum, off, 64);
            if (lane == 0) WcT[o * K_DIM + k] = sum;
        } else {                                  // w in [2560,2568): bias fold
            const int o = w - 2560;
            #pragma unroll
            for (int it = 0; it < H_DIM / 64; ++it) {
                const int j = lane + it * 64;
                sum += b_mora[j] * W_post[j * OUT_DIM + o];
            }
            #pragma unroll
            for (int off = 32; off >= 1; off >>= 1) sum += __shfl_down(sum, off, 64);
            if (lane == 0) bc[o] = sum + b_post[o];
        }
    } else {
        const int t = (blk - 642) * 256 + tid;    // 0 .. B*F-1
        const int b = t >> 12;                    // /4096
        const int f = t & (F_DIM - 1);
        const int* mi = mora_index + b * F_DIM;
        const int cur = mi[f];
        int* sg = seg + b * (M_DIM + 1);
        if (f == 0) {
            for (int m = 0; m <= cur; ++m) sg[m] = 0;
        } else {
            const int prev = mi[f - 1];
            for (int m = prev + 1; m <= cur; ++m) sg[m] = f;
        }
        if (f == F_DIM - 1) {
            for (int m = cur + 1; m <= M_DIM; ++m) sg[m] = F_DIM;
        }
    }
}

// ---------------------------------------------------------------------------
// Kernel 2 (main): one block per 8 consecutive moras of one batch.
//  - segment mean over the mora's contiguous frame range (float4 loads, 16B/lane;
//    one frame = 256 floats = exactly 64 lanes x float4, perfectly coalesced)
//  - out[b,m,:] = concat(emb[vowel], mean) . WcT + bc   (K=320 -> 8)
// ---------------------------------------------------------------------------
__global__ __launch_bounds__(256) void main_kernel(
    const int* __restrict__ vowels,              // [B,M]
    const float* __restrict__ features,          // [B,F,D] fp32
    const float* __restrict__ emb,               // [V,VE] fp32
    const float* __restrict__ WcT,               // [8,320]
    const float* __restrict__ bc,                // [8]
    const int* __restrict__ seg,                 // [B,513]
    float* __restrict__ out)                     // [B,M,8] fp32
{
    __shared__ float sWcT[OUT_DIM * K_DIM];                 // 10 KB, [o][k]
    __shared__ float sbc[OUT_DIM];
    __shared__ float sx[K_DIM];                             // concat(mv, mean)
    __shared__ __align__(16) float sred[4 * 256];           // cross-wave partials
    __shared__ float spart[4 * OUT_DIM];
    __shared__ int   sbounds[9];

    const int b   = blockIdx.x >> 6;             // 64 blocks per batch
    const int m0  = (blockIdx.x & 63) * 8;
    const int tid = threadIdx.x;
    const int lane = tid & 63;
    const int wv   = tid >> 6;

    for (int i = tid; i < OUT_DIM * K_DIM; i += 256) sWcT[i] = WcT[i];
    if (tid < OUT_DIM) sbc[tid] = bc[tid];
    if (tid < 9) sbounds[tid] = seg[b * (M_DIM + 1) + m0 + tid];
    __syncthreads();

    const float4* feat4 = (const float4*)features + (size_t)b * F_DIM * (D_DIM / 4);
    const int q = lane;                          // d-quad: d = 4q..4q+3
    const int g = wv;                            // frame phase 0..3

    for (int mm = 0; mm < 8; ++mm) {
        const int fs = sbounds[mm], fe = sbounds[mm + 1];
        const int cnt = fe - fs;

        float a0 = 0.f, a1 = 0.f, a2 = 0.f, a3 = 0.f;
        for (int f = fs + g; f < fe; f += 4) {
            const float4 v = feat4[f * 64 + q];
            a0 += v.x; a1 += v.y; a2 += v.z; a3 += v.w;
        }
        *(float4*)&sred[g * 256 + q * 4] = make_float4(a0, a1, a2, a3);
        __syncthreads();

        const float inv = (cnt > 0) ? 1.0f / (float)cnt : 0.0f;
        const float s = sred[tid] + sred[256 + tid] + sred[512 + tid] + sred[768 + tid];
        sx[VE_DIM + tid] = s * inv;              // mean part: k = 64..319
        if (tid < VE_DIM) {
            const int vw = vowels[b * M_DIM + m0 + mm];   // broadcast load
            sx[tid] = emb[vw * VE_DIM + tid];             // mv part: k = 0..63
        }
        __syncthreads();

        float p[OUT_DIM];
        {
            const float xk = sx[tid];
            #pragma unroll
            for (int o = 0; o < OUT_DIM; ++o) p[o] = xk * sWcT[o * K_DIM + tid];
            if (tid < 64) {
                const float xk2 = sx[256 + tid];
                #pragma unroll
                for (int o = 0; o < OUT_DIM; ++o) p[o] += xk2 * sWcT[o * K_DIM + 256 + tid];
            }
        }
        #pragma unroll
        for (int off = 32; off >= 1; off >>= 1) {
            #pragma unroll
            for (int o = 0; o < OUT_DIM; ++o) p[o] += __shfl_down(p[o], off, 64);
        }
        if (lane == 0) {
            #pragma unroll
            for (int o = 0; o < OUT_DIM; ++o) spart[wv * OUT_DIM + o] = p[o];
        }
        __syncthreads();
        if (tid < OUT_DIM) {
            const float r = spart[tid] + spart[8 + tid] + spart[16 + tid] + spart[24 + tid]
                          + sbc[tid];
            out[(size_t)(b * M_DIM + m0 + mm) * OUT_DIM + tid] = r;
        }
        __syncthreads();                          // protect sred/sx/spart reuse
    }
}

extern "C" void kernel_launch(void* const* d_in, const int* in_sizes, int n_in,
                              void* d_out, int out_size, void* d_ws, size_t ws_size,
                              hipStream_t stream) {
    const int*   vowels     = (const int*)d_in[0];
    const float* features   = (const float*)d_in[1];
    const int*   mora_index = (const int*)d_in[2];
    const float* emb        = (const float*)d_in[3];
    const float* W_mora     = (const float*)d_in[4];
    const float* b_mora     = (const float*)d_in[5];
    // d_in[6] = W_frame, d_in[7] = b_frame: dead code in the reference (fh is deleted)
    const float* W_post     = (const float*)d_in[8];
    const float* b_post     = (const float*)d_in[9];
    float*       out        = (float*)d_out;

    float* WcT = (float*)d_ws;                   // 8*320 fp32
    float* bc  = WcT + OUT_DIM * K_DIM;          // 8 fp32
    int*   seg = (int*)(bc + OUT_DIM);           // B*(M+1) int32

    prep_kernel<<<642 + (B_DIM * F_DIM) / 256, 256, 0, stream>>>(
        W_mora, b_mora, W_post, b_post, mora_index, WcT, bc, seg);
    main_kernel<<<(B_DIM * M_DIM) / 8, 256, 0, stream>>>(
        vowels, features, emb, WcT, bc, seg, out);
}

// Round 3
// 133.450 us; speedup vs baseline: 1.0144x; 1.0144x over previous
//
#include <hip/hip_runtime.h>

// Shapes (fixed by the reference): B=16, F=4096, M=512, D=256, VE=64, H=512, V=50, OUT=8
#define B_DIM  16
#define F_DIM  4096
#define M_DIM  512
#define D_DIM  256
#define VE_DIM 64
#define H_DIM  512
#define K_DIM  320   // D + VE
#define OUT_DIM 8
#define MPB    4     // moras per block (main kernel)
#define UNROLL 8     // outstanding float4 loads per thread per batch

// ---------------------------------------------------------------------------
// Kernel 1 (prep):
//  blocks [0,642):   fold WcT[o][k] = sum_j W_mora[k,j] * W_post[j,o]   (wave per (k,o))
//                    and bc[o] = sum_j b_mora[j]*W_post[j,o] + b_post[o]
//  blocks [642,898): seg[b][m] = lower_bound(mora_index[b,:], m) via boundary detection
//                    (mora_index is sorted per batch); seg[b][M] = F
// ---------------------------------------------------------------------------
__global__ __launch_bounds__(256) void prep_kernel(
    const float* __restrict__ W_mora,            // [320,512]
    const float* __restrict__ b_mora,            // [512]
    const float* __restrict__ W_post,            // [512,8]
    const float* __restrict__ b_post,            // [8]
    const int* __restrict__ mora_index,          // [B,F] sorted per batch
    float* __restrict__ WcT,                     // [8,320] out
    float* __restrict__ bc,                      // [8] out
    int* __restrict__ seg)                       // [B,513] out
{
    const int blk = blockIdx.x;
    const int tid = threadIdx.x;
    if (blk < 642) {
        const int w    = blk * 4 + (tid >> 6);   // global wave id
        const int lane = tid & 63;
        float sum = 0.f;
        if (w < 2560) {
            const int k = w >> 3, o = w & 7;
            const float* arow = W_mora + k * H_DIM;
            #pragma unroll
            for (int it = 0; it < H_DIM / 64; ++it) {
                const int j = lane + it * 64;
                sum += arow[j] * W_post[j * OUT_DIM + o];
            }
            #pragma unroll
            for (int off = 32; off >= 1; off >>= 1) sum += __shfl_down(sum, off, 64);
            if (lane == 0) WcT[o * K_DIM + k] = sum;
        } else if (w < 2568) {                    // bias fold
            const int o = w - 2560;
            #pragma unroll
            for (int it = 0; it < H_DIM / 64; ++it) {
                const int j = lane + it * 64;
                sum += b_mora[j] * W_post[j * OUT_DIM + o];
            }
            #pragma unroll
            for (int off = 32; off >= 1; off >>= 1) sum += __shfl_down(sum, off, 64);
            if (lane == 0) bc[o] = sum + b_post[o];
        }
    } else {
        const int t = (blk - 642) * 256 + tid;    // 0 .. B*F-1
        const int b = t >> 12;                    // /4096
        const int f = t & (F_DIM - 1);
        const int* mi = mora_index + b * F_DIM;
        const int cur = mi[f];
        int* sg = seg + b * (M_DIM + 1);
        if (f == 0) {
            for (int m = 0; m <= cur; ++m) sg[m] = 0;
        } else {
            const int prev = mi[f - 1];
            for (int m = prev + 1; m <= cur; ++m) sg[m] = f;
        }
        if (f == F_DIM - 1) {
            for (int m = cur + 1; m <= M_DIM; ++m) sg[m] = F_DIM;
        }
    }
}

// ---------------------------------------------------------------------------
// Kernel 2 (main): one block per 4 consecutive moras of one batch.
//  Phase A: segment sums. Block's frame range [seg[m0], seg[m0+4]) is split into
//           4 contiguous per-wave strips; each wave issues UNROLL unconditional
//           float4 loads per batch (high MLP), tracks mora boundaries from LDS
//           sbounds (no per-frame index loads), flushes acc to LDS atomically.
//  Phase B: one wave per mora: x = concat(emb[vowel], sum/cnt); out = x.WcT + bc.
// ---------------------------------------------------------------------------
__global__ __launch_bounds__(256) void main_kernel(
    const int* __restrict__ vowels,              // [B,M]
    const float* __restrict__ features,          // [B,F,D]
    const float* __restrict__ emb,               // [V,VE]
    const float* __restrict__ WcT,               // [8,320]
    const float* __restrict__ bc,                // [8]
    const int* __restrict__ seg,                 // [B,513]
    float* __restrict__ out)                     // [B,M,8]
{
    __shared__ float sWcT[OUT_DIM * K_DIM];      // 10 KB
    __shared__ float sums[MPB][D_DIM];           // 4 KB
    __shared__ float sbc[OUT_DIM];
    __shared__ int   sbounds[MPB + 1];

    const int b    = blockIdx.x >> 7;            // 128 blocks per batch
    const int m0   = (blockIdx.x & 127) * MPB;
    const int tid  = threadIdx.x;
    const int lane = tid & 63;
    const int wv   = tid >> 6;

    for (int i = tid; i < OUT_DIM * K_DIM / 4; i += 256)
        ((float4*)sWcT)[i] = ((const float4*)WcT)[i];
    if (tid < OUT_DIM) sbc[tid] = bc[tid];
    if (tid <= MPB) sbounds[tid] = seg[b * (M_DIM + 1) + m0 + tid];
    for (int i = tid; i < MPB * D_DIM; i += 256) ((float*)sums)[i] = 0.f;
    __syncthreads();

    const float4* feat4 = (const float4*)features + (size_t)b * F_DIM * (D_DIM / 4);
    const int fs0 = sbounds[0], fe = sbounds[MPB];
    const int len = fe - fs0;
    const int s_g = fs0 + ((len * wv) >> 2);     // this wave's contiguous strip
    const int e_g = fs0 + ((len * (wv + 1)) >> 2);

    if (s_g < e_g) {
        int mm = 0;
        while (sbounds[mm + 1] <= s_g) ++mm;     // mora containing first frame
        float a0 = 0.f, a1 = 0.f, a2 = 0.f, a3 = 0.f;
        int f = s_g;
        // full batches: UNROLL unconditional independent loads, then walk
        for (; f + UNROLL <= e_g; f += UNROLL) {
            float4 v[UNROLL];
            #pragma unroll
            for (int i = 0; i < UNROLL; ++i)
                v[i] = feat4[(size_t)(f + i) * 64 + lane];
            #pragma unroll
            for (int i = 0; i < UNROLL; ++i) {
                const int ff = f + i;
                if (ff >= sbounds[mm + 1]) {
                    atomicAdd(&sums[mm][lane * 4 + 0], a0);
                    atomicAdd(&sums[mm][lane * 4 + 1], a1);
                    atomicAdd(&sums[mm][lane * 4 + 2], a2);
                    atomicAdd(&sums[mm][lane * 4 + 3], a3);
                    a0 = a1 = a2 = a3 = 0.f;
                    do { ++mm; } while (sbounds[mm + 1] <= ff);
                }
                a0 += v[i].x; a1 += v[i].y; a2 += v[i].z; a3 += v[i].w;
            }
        }
        // remainder
        for (; f < e_g; ++f) {
            const float4 v = feat4[(size_t)f * 64 + lane];
            if (f >= sbounds[mm + 1]) {
                atomicAdd(&sums[mm][lane * 4 + 0], a0);
                atomicAdd(&sums[mm][lane * 4 + 1], a1);
                atomicAdd(&sums[mm][lane * 4 + 2], a2);
                atomicAdd(&sums[mm][lane * 4 + 3], a3);
                a0 = a1 = a2 = a3 = 0.f;
                do { ++mm; } while (sbounds[mm + 1] <= f);
            }
            a0 += v.x; a1 += v.y; a2 += v.z; a3 += v.w;
        }
        atomicAdd(&sums[mm][lane * 4 + 0], a0);
        atomicAdd(&sums[mm][lane * 4 + 1], a1);
        atomicAdd(&sums[mm][lane * 4 + 2], a2);
        atomicAdd(&sums[mm][lane * 4 + 3], a3);
    }
    __syncthreads();

    // Phase B: wave wv -> mora m0+wv
    {
        const int m   = m0 + wv;
        const int cnt = sbounds[wv + 1] - sbounds[wv];
        const float inv = (cnt > 0) ? 1.0f / (float)cnt : 0.0f;
        const int vw  = vowels[b * M_DIM + m];    // broadcast
        float p[OUT_DIM];
        const float x0 = emb[vw * VE_DIM + lane]; // k = lane (emb part)
        #pragma unroll
        for (int o = 0; o < OUT_DIM; ++o) p[o] = x0 * sWcT[o * K_DIM + lane];
        #pragma unroll
        for (int j = 1; j < 5; ++j) {
            const int k = lane + 64 * j;          // k = 64..319 (mean part)
            const float x = sums[wv][k - VE_DIM] * inv;
            #pragma unroll
            for (int o = 0; o < OUT_DIM; ++o) p[o] += x * sWcT[o * K_DIM + k];
        }
        #pragma unroll
        for (int off = 32; off >= 1; off >>= 1) {
            #pragma unroll
            for (int o = 0; o < OUT_DIM; ++o) p[o] += __shfl_down(p[o], off, 64);
        }
        if (lane == 0) {
            #pragma unroll
            for (int o = 0; o < OUT_DIM; ++o)
                out[(size_t)(b * M_DIM + m) * OUT_DIM + o] = p[o] + sbc[o];
        }
    }
}

extern "C" void kernel_launch(void* const* d_in, const int* in_sizes, int n_in,
                              void* d_out, int out_size, void* d_ws, size_t ws_size,
                              hipStream_t stream) {
    const int*   vowels     = (const int*)d_in[0];
    const float* features   = (const float*)d_in[1];
    const int*   mora_index = (const int*)d_in[2];
    const float* emb        = (const float*)d_in[3];
    const float* W_mora     = (const float*)d_in[4];
    const float* b_mora     = (const float*)d_in[5];
    // d_in[6] = W_frame, d_in[7] = b_frame: dead code in the reference (fh is deleted)
    const float* W_post     = (const float*)d_in[8];
    const float* b_post     = (const float*)d_in[9];
    float*       out        = (float*)d_out;

    float* WcT = (float*)d_ws;                   // 8*320 fp32
    float* bc  = WcT + OUT_DIM * K_DIM;          // 8 fp32
    int*   seg = (int*)(bc + OUT_DIM);           // B*(M+1) int32

    prep_kernel<<<642 + (B_DIM * F_DIM) / 256, 256, 0, stream>>>(
        W_mora, b_mora, W_post, b_post, mora_index, WcT, bc, seg);
    main_kernel<<<(B_DIM * M_DIM) / MPB, 256, 0, stream>>>(
        vowels, features, emb, WcT, bc, seg, out);
}